// Round 9
// baseline (596.007 us; speedup 1.0000x reference)
//
#include <hip/hip_runtime.h>
#include <hip/hip_bf16.h>
#include <cstdint>

#define C_DIM 128
#define E_DIM 64
#define B_DIM 8192

typedef __attribute__((ext_vector_type(8))) short short8;
typedef __attribute__((ext_vector_type(4))) float f32x4;

union Frag8 { short8 v; short s[8]; uint32_t u[4]; };

__device__ __forceinline__ unsigned short bfbits(float x) {
    union { __hip_bfloat16 h; unsigned short u; } cv;
    cv.h = __float2bfloat16(x);
    return cv.u;
}
__device__ __forceinline__ float bits2f(unsigned short b) {
    return __uint_as_float(((uint32_t)b) << 16);
}

// ---------- K0: w = softmax(q,axis=1), zero diag, split hi/lo bf16, layout [c][n] ----------
__global__ __launch_bounds__(128) void k0_softmax(const float* __restrict__ q,
                                                  unsigned short* __restrict__ whi,
                                                  unsigned short* __restrict__ wlo) {
    const int c = blockIdx.x;
    const int t = threadIdx.x;            // n
    __shared__ float redM[2], redS[2];
    float v = q[c * C_DIM + t];
    float m = v;
    #pragma unroll
    for (int o = 32; o > 0; o >>= 1) m = fmaxf(m, __shfl_xor(m, o));
    if ((t & 63) == 0) redM[t >> 6] = m;
    __syncthreads();
    m = fmaxf(redM[0], redM[1]);
    float e = expf(v - m);
    float s = e;
    #pragma unroll
    for (int o = 32; o > 0; o >>= 1) s += __shfl_xor(s, o);
    if ((t & 63) == 0) redS[t >> 6] = s;
    __syncthreads();
    s = redS[0] + redS[1];
    float w = e / s;
    if (t == c) w = 0.f;                  // zero diagonal AFTER softmax
    unsigned short hb = bfbits(w);
    whi[c * C_DIM + t] = hb;
    wlo[c * C_DIM + t] = bfbits(w - bits2f(hb));
}

// ---------- KP: elementwise hi/lo bf16 split of a f32 weight tensor ----------
__global__ __launch_bounds__(256) void kP_split(const float* __restrict__ src,
                                                unsigned short* __restrict__ hi,
                                                unsigned short* __restrict__ lo) {
    const int i = blockIdx.x * 256 + threadIdx.x;   // index in float4 units
    const float4 v = ((const float4*)src)[i];
    float f[4] = {v.x, v.y, v.z, v.w};
    unsigned short h[4], l[4];
    #pragma unroll
    for (int j = 0; j < 4; ++j) {
        h[j] = bfbits(f[j]);
        l[j] = bfbits(f[j] - bits2f(h[j]));
    }
    ((ushort4*)hi)[i] = make_ushort4(h[0], h[1], h[2], h[3]);
    ((ushort4*)lo)[i] = make_ushort4(l[0], l[1], l[2], l[3]);
}

// ---------- KF: fully fused. block = 8 rows x 128 cols, 8 waves, 128KB LDS ----------
// phase 1: value MLP + L2 norm -> V-LDS [r][n8][e][8n] (e-field ^ (r&7)<<4)
// phase 2: mixing, wave = row    -> ctx regs -> ctx-LDS [r][c][e] (^((r^c)&7)<<4)
// phase 3: projection, 16 cols/wave -> out
__global__ __launch_bounds__(512, 2) void kF_fused(
        const float* __restrict__ samples,
        const float* __restrict__ W1, const float* __restrict__ b1,
        const unsigned short* __restrict__ W2hi, const unsigned short* __restrict__ W2lo,
        const float* __restrict__ b2,
        const unsigned short* __restrict__ whi, const unsigned short* __restrict__ wlo,
        const unsigned short* __restrict__ P1hi, const unsigned short* __restrict__ P1lo,
        const float* __restrict__ pb1, const float* __restrict__ P2,
        const float* __restrict__ pb2, float* __restrict__ out) {
    __shared__ char sBuf[131072];          // V then ctx, 16 KB per row
    const int t = threadIdx.x;
    const int lane = t & 63, wv = t >> 6;
    const int lm = lane & 15, lg = lane >> 4;
    const int R0 = blockIdx.x * 8;
    const int rA = lm & 7;                 // A-side row (rows 8..15 duplicate 0..7)

    // ---------------- phase 1: value MLP for this wave's 16 columns ----------------
    #pragma unroll 1
    for (int cc = 0; cc < 16; ++cc) {
        const int c = wv * 16 + cc;
        const float sv = samples[(size_t)(R0 + rA) * C_DIM + c];

        float w1r[2][8], b1r[2][8];
        #pragma unroll
        for (int ks = 0; ks < 2; ++ks) {
            const float4 wa = *(const float4*)(W1 + (size_t)c * 64 + ks * 32 + lg * 8);
            const float4 wb = *(const float4*)(W1 + (size_t)c * 64 + ks * 32 + lg * 8 + 4);
            const float4 ba = *(const float4*)(b1 + (size_t)c * 64 + ks * 32 + lg * 8);
            const float4 bb = *(const float4*)(b1 + (size_t)c * 64 + ks * 32 + lg * 8 + 4);
            w1r[ks][0] = wa.x; w1r[ks][1] = wa.y; w1r[ks][2] = wa.z; w1r[ks][3] = wa.w;
            w1r[ks][4] = wb.x; w1r[ks][5] = wb.y; w1r[ks][6] = wb.z; w1r[ks][7] = wb.w;
            b1r[ks][0] = ba.x; b1r[ks][1] = ba.y; b1r[ks][2] = ba.z; b1r[ks][3] = ba.w;
            b1r[ks][4] = bb.x; b1r[ks][5] = bb.y; b1r[ks][6] = bb.z; b1r[ks][7] = bb.w;
        }
        float b2r[4];
        #pragma unroll
        for (int nt = 0; nt < 4; ++nt) b2r[nt] = b2[(size_t)c * 64 + nt * 16 + lm];

        f32x4 acc[4];
        #pragma unroll
        for (int nt = 0; nt < 4; ++nt) acc[nt] = (f32x4){0.f, 0.f, 0.f, 0.f};

        #pragma unroll
        for (int ks = 0; ks < 2; ++ks) {
            Frag8 af;
            #pragma unroll
            for (int j = 0; j < 8; ++j)
                af.s[j] = (short)bfbits(fmaxf(fmaf(sv, w1r[ks][j], b1r[ks][j]), 0.f));
            #pragma unroll
            for (int nt = 0; nt < 4; ++nt) {
                const size_t wb = ((size_t)c * 64 + nt * 16 + lm) * 64 + ks * 32 + lg * 8;
                const short8 bh = *(const short8*)(W2hi + wb);
                const short8 bl = *(const short8*)(W2lo + wb);
                acc[nt] = __builtin_amdgcn_mfma_f32_16x16x32_bf16(af.v, bh, acc[nt], 0, 0, 0);
                acc[nt] = __builtin_amdgcn_mfma_f32_16x16x32_bf16(af.v, bl, acc[nt], 0, 0, 0);
            }
        }

        // add b2, L2-norm over f (lane-local nt + butterfly over lm)
        float rsc[4];
        #pragma unroll
        for (int i = 0; i < 4; ++i) {
            float s2 = 0.f;
            #pragma unroll
            for (int nt = 0; nt < 4; ++nt) {
                const float vv = acc[nt][i] + b2r[nt];
                acc[nt][i] = vv;
                s2 = fmaf(vv, vv, s2);
            }
            s2 += __shfl_xor(s2, 1); s2 += __shfl_xor(s2, 2);
            s2 += __shfl_xor(s2, 4); s2 += __shfl_xor(s2, 8);
            rsc[i] = 1.f / fmaxf(sqrtf(s2), 1e-12f);
        }

        // write V[r][n8][f][c&7] bf16 (rows lg<2 only)
        if (lg < 2) {
            #pragma unroll
            for (int nt = 0; nt < 4; ++nt)
                #pragma unroll
                for (int i = 0; i < 4; ++i) {
                    const int r = lg * 4 + i;
                    const int f = nt * 16 + lm;
                    const uint32_t bo = (uint32_t)r * 16384u + (uint32_t)(c >> 3) * 1024u +
                                        (((uint32_t)f * 16u) ^ ((uint32_t)(r & 7) << 4)) +
                                        (uint32_t)(c & 7) * 2u;
                    *(unsigned short*)(sBuf + bo) = bfbits(acc[nt][i] * rsc[i]);
                }
        }
    }
    __syncthreads();

    // ---------------- phase 2: mixing for row r = wv ----------------
    {
        const int r = wv;
        const char* vbase = sBuf + (size_t)r * 16384;
        const uint32_t eswz = (uint32_t)(r & 7) << 4;

        f32x4 acc[4][8];                   // [et][nt]
        #pragma unroll
        for (int et = 0; et < 4; ++et)
            #pragma unroll
            for (int nt = 0; nt < 8; ++nt)
                acc[et][nt] = (f32x4){0.f, 0.f, 0.f, 0.f};

#define LDVF(KS, ET) (*(const short8*)(vbase + ((KS) * 4 + lg) * 1024 + \
                        ((((uint32_t)((ET) * 16 + lm)) * 16u) ^ eswz)))
        short8 vA0 = LDVF(0, 0), vA1 = LDVF(0, 1), vA2 = LDVF(0, 2), vA3 = LDVF(0, 3);
        short8 vB0, vB1, vB2, vB3;

#define P2_STEP(KS, C0, C1, C2, C3, N0, N1, N2, N3, PF)                                    \
        {                                                                                  \
            if (PF) { N0 = LDVF(KS + 1, 0); N1 = LDVF(KS + 1, 1);                          \
                      N2 = LDVF(KS + 1, 2); N3 = LDVF(KS + 1, 3); }                        \
            _Pragma("unroll")                                                              \
            for (int nt = 0; nt < 8; ++nt) {                                               \
                const size_t wb = (size_t)(nt * 16 + lm) * C_DIM + (KS) * 32 + lg * 8;     \
                const short8 bh = *(const short8*)(whi + wb);                              \
                const short8 bl = *(const short8*)(wlo + wb);                              \
                acc[0][nt] = __builtin_amdgcn_mfma_f32_16x16x32_bf16(C0, bh, acc[0][nt], 0, 0, 0); \
                acc[0][nt] = __builtin_amdgcn_mfma_f32_16x16x32_bf16(C0, bl, acc[0][nt], 0, 0, 0); \
                acc[1][nt] = __builtin_amdgcn_mfma_f32_16x16x32_bf16(C1, bh, acc[1][nt], 0, 0, 0); \
                acc[1][nt] = __builtin_amdgcn_mfma_f32_16x16x32_bf16(C1, bl, acc[1][nt], 0, 0, 0); \
                acc[2][nt] = __builtin_amdgcn_mfma_f32_16x16x32_bf16(C2, bh, acc[2][nt], 0, 0, 0); \
                acc[2][nt] = __builtin_amdgcn_mfma_f32_16x16x32_bf16(C2, bl, acc[2][nt], 0, 0, 0); \
                acc[3][nt] = __builtin_amdgcn_mfma_f32_16x16x32_bf16(C3, bh, acc[3][nt], 0, 0, 0); \
                acc[3][nt] = __builtin_amdgcn_mfma_f32_16x16x32_bf16(C3, bl, acc[3][nt], 0, 0, 0); \
            }                                                                              \
        }
        P2_STEP(0, vA0, vA1, vA2, vA3, vB0, vB1, vB2, vB3, 1)
        P2_STEP(1, vB0, vB1, vB2, vB3, vA0, vA1, vA2, vA3, 1)
        P2_STEP(2, vA0, vA1, vA2, vA3, vB0, vB1, vB2, vB3, 1)
        P2_STEP(3, vB0, vB1, vB2, vB3, vA0, vA1, vA2, vA3, 0)
#undef P2_STEP
#undef LDVF

        // write ctx[r][c][e] bf16 over this row's own 16 KB region (no cross-wave hazard)
        #pragma unroll
        for (int et = 0; et < 4; ++et)
            #pragma unroll
            for (int nt = 0; nt < 8; ++nt) {
                const int cloc = nt * 16 + lm;
                const uint32_t u0 = (uint32_t)bfbits(acc[et][nt][0]) | ((uint32_t)bfbits(acc[et][nt][1]) << 16);
                const uint32_t u1 = (uint32_t)bfbits(acc[et][nt][2]) | ((uint32_t)bfbits(acc[et][nt][3]) << 16);
                uint32_t bo = (uint32_t)r * 16384u + (uint32_t)cloc * 128u +
                              (uint32_t)(et * 32 + lg * 8);
                bo ^= (uint32_t)((r ^ cloc) & 7) << 4;
                *(uint2*)(sBuf + bo) = make_uint2(u0, u1);
            }
    }
    __syncthreads();

    // ---------------- phase 3: projection for this wave's 16 columns ----------------
    #pragma unroll 1
    for (int cc = 0; cc < 16; ++cc) {
        const int c = wv * 16 + cc;

        float pb1r[4], p2r[4];
        #pragma unroll
        for (int nt = 0; nt < 4; ++nt) {
            pb1r[nt] = pb1[(size_t)c * 64 + nt * 16 + lm];
            p2r[nt]  = P2[(size_t)c * 64 + nt * 16 + lm];
        }
        const float pb2c = pb2[c];

        f32x4 acc2[4];
        #pragma unroll
        for (int nt = 0; nt < 4; ++nt) acc2[nt] = (f32x4){0.f, 0.f, 0.f, 0.f};

        #pragma unroll
        for (int ks = 0; ks < 2; ++ks) {
            const int rl = lm & 7;          // rows 8..15 of M-tile duplicate 0..7
            uint32_t bo = (uint32_t)rl * 16384u + (uint32_t)c * 128u +
                          (uint32_t)(ks * 64 + lg * 16);
            bo ^= (uint32_t)((rl ^ c) & 7) << 4;
            const short8 a0 = *(const short8*)(sBuf + bo);
            #pragma unroll
            for (int nt = 0; nt < 4; ++nt) {
                const size_t wb = ((size_t)c * 64 + nt * 16 + lm) * 64 + ks * 32 + lg * 8;
                const short8 bh = *(const short8*)(P1hi + wb);
                const short8 bl = *(const short8*)(P1lo + wb);
                acc2[nt] = __builtin_amdgcn_mfma_f32_16x16x32_bf16(a0, bh, acc2[nt], 0, 0, 0);
                acc2[nt] = __builtin_amdgcn_mfma_f32_16x16x32_bf16(a0, bl, acc2[nt], 0, 0, 0);
            }
        }

        // epilogue: relu, dot with P2 over f, butterfly over lm, store valid rows (lg<2)
        #pragma unroll
        for (int i = 0; i < 4; ++i) {
            float p = 0.f;
            #pragma unroll
            for (int nt = 0; nt < 4; ++nt)
                p = fmaf(fmaxf(acc2[nt][i] + pb1r[nt], 0.f), p2r[nt], p);
            p += __shfl_xor(p, 1); p += __shfl_xor(p, 2);
            p += __shfl_xor(p, 4); p += __shfl_xor(p, 8);
            if (lm == 0 && lg < 2)
                out[(size_t)(R0 + lg * 4 + i) * C_DIM + c] = p + pb2c;
        }
    }
}

// ---------- host ----------
extern "C" void kernel_launch(void* const* d_in, const int* in_sizes, int n_in,
                              void* d_out, int out_size, void* d_ws, size_t ws_size,
                              hipStream_t stream) {
    const float* samples = (const float*)d_in[0];
    const float* W1  = (const float*)d_in[1];
    const float* b1  = (const float*)d_in[2];
    const float* W2  = (const float*)d_in[3];
    const float* b2  = (const float*)d_in[4];
    const float* q   = (const float*)d_in[5];
    const float* P1  = (const float*)d_in[6];
    const float* pb1 = (const float*)d_in[7];
    const float* P2  = (const float*)d_in[8];
    const float* pb2 = (const float*)d_in[9];
    float* out = (float*)d_out;

    char* ws = (char*)d_ws;
    unsigned short* whi  = (unsigned short*)ws;                       // 32KB
    unsigned short* wlo  = (unsigned short*)(ws + 32768);             // 32KB
    unsigned short* W2hi = (unsigned short*)(ws + 65536);             // 1MB
    unsigned short* W2lo = (unsigned short*)(ws + 65536 + 1048576);   // 1MB
    unsigned short* P1hi = (unsigned short*)(ws + 65536 + 2097152);   // 1MB
    unsigned short* P1lo = (unsigned short*)(ws + 65536 + 3145728);   // 1MB

    k0_softmax<<<dim3(C_DIM), dim3(C_DIM), 0, stream>>>(q, whi, wlo);
    kP_split<<<dim3(512), 256, 0, stream>>>(W2, W2hi, W2lo);   // 524288 floats / 4 / 256
    kP_split<<<dim3(512), 256, 0, stream>>>(P1, P1hi, P1lo);

    kF_fused<<<dim3(B_DIM / 8), 512, 0, stream>>>(samples, W1, b1, W2hi, W2lo, b2,
                                                  whi, wlo, P1hi, P1lo, pb1, P2, pb2, out);
}

// Round 10
// 353.272 us; speedup vs baseline: 1.6871x; 1.6871x over previous
//
#include <hip/hip_runtime.h>
#include <hip/hip_bf16.h>
#include <cstdint>

#define C_DIM 128
#define E_DIM 64
#define B_DIM 8192

typedef __attribute__((ext_vector_type(8))) short short8;
typedef __attribute__((ext_vector_type(4))) float f32x4;

union Frag8 { short8 v; short s[8]; uint32_t u[4]; };

__device__ __forceinline__ unsigned short bfbits(float x) {
    union { __hip_bfloat16 h; unsigned short u; } cv;
    cv.h = __float2bfloat16(x);
    return cv.u;
}
__device__ __forceinline__ float bits2f(unsigned short b) {
    return __uint_as_float(((uint32_t)b) << 16);
}

// ---------- K0: w = softmax(q,axis=1), zero diag, split hi/lo bf16, layout [c][n] ----------
__global__ __launch_bounds__(128) void k0_softmax(const float* __restrict__ q,
                                                  unsigned short* __restrict__ whi,
                                                  unsigned short* __restrict__ wlo) {
    const int c = blockIdx.x;
    const int t = threadIdx.x;            // n
    __shared__ float redM[2], redS[2];
    float v = q[c * C_DIM + t];
    float m = v;
    #pragma unroll
    for (int o = 32; o > 0; o >>= 1) m = fmaxf(m, __shfl_xor(m, o));
    if ((t & 63) == 0) redM[t >> 6] = m;
    __syncthreads();
    m = fmaxf(redM[0], redM[1]);
    float e = expf(v - m);
    float s = e;
    #pragma unroll
    for (int o = 32; o > 0; o >>= 1) s += __shfl_xor(s, o);
    if ((t & 63) == 0) redS[t >> 6] = s;
    __syncthreads();
    s = redS[0] + redS[1];
    float w = e / s;
    if (t == c) w = 0.f;                  // zero diagonal AFTER softmax
    unsigned short hb = bfbits(w);
    whi[c * C_DIM + t] = hb;
    wlo[c * C_DIM + t] = bfbits(w - bits2f(hb));
}

// ---------- KP: elementwise hi/lo bf16 split of a f32 weight tensor ----------
__global__ __launch_bounds__(256) void kP_split(const float* __restrict__ src,
                                                unsigned short* __restrict__ hi,
                                                unsigned short* __restrict__ lo) {
    const int i = blockIdx.x * 256 + threadIdx.x;   // index in float4 units
    const float4 v = ((const float4*)src)[i];
    float f[4] = {v.x, v.y, v.z, v.w};
    unsigned short h[4], l[4];
    #pragma unroll
    for (int j = 0; j < 4; ++j) {
        h[j] = bfbits(f[j]);
        l[j] = bfbits(f[j] - bits2f(h[j]));
    }
    ((ushort4*)hi)[i] = make_ushort4(h[0], h[1], h[2], h[3]);
    ((ushort4*)lo)[i] = make_ushort4(l[0], l[1], l[2], l[3]);
}

// ---------- K1: value MLP + L2 norm, MFMA. Output V[r][n8][e][8n] bf16 ----------
// block = 64 rows x 8 columns, 8 waves (1 column each). D: m=r, n=f.
__global__ __launch_bounds__(512, 4) void k1_value(
        const float* __restrict__ samples, const float* __restrict__ W1,
        const float* __restrict__ b1, const unsigned short* __restrict__ W2hi,
        const unsigned short* __restrict__ W2lo, const float* __restrict__ b2,
        uint32_t* __restrict__ vbuf, int rowOff) {
    __shared__ char sOut[32 * 1024];       // [r32][f][c_local] bf16, XOR-swizzled
    const int t = threadIdx.x;
    const int rt = blockIdx.x, cg = blockIdx.y;
    const int r0 = rt * 64;
    const int cl = t >> 6;                 // wave = local column
    const int lane = t & 63;
    const int lm = lane & 15, lg = lane >> 4;
    const int c = cg * 8 + cl;

    // scatter sample loads issued first (deepest latency)
    float sv[4];
    #pragma unroll
    for (int mt = 0; mt < 4; ++mt)
        sv[mt] = samples[(size_t)(rowOff + r0 + mt * 16 + lm) * C_DIM + c];

    float b2r[4];
    #pragma unroll
    for (int nt = 0; nt < 4; ++nt) b2r[nt] = b2[(size_t)c * 64 + nt * 16 + lm];

    f32x4 acc[4][4];
    #pragma unroll
    for (int mt = 0; mt < 4; ++mt)
        #pragma unroll
        for (int nt = 0; nt < 4; ++nt)
            acc[mt][nt] = (f32x4){0.f, 0.f, 0.f, 0.f};

    #pragma unroll
    for (int ks = 0; ks < 2; ++ks) {
        const size_t wbase = ((size_t)c * 64) * 64 + ks * 32 + lg * 8;

        // rotating double-buffer of B-frag pairs (static names, rule #20)
        short8 bhA = *(const short8*)(W2hi + wbase + (size_t)(0 * 16 + lm) * 64);
        short8 blA = *(const short8*)(W2lo + wbase + (size_t)(0 * 16 + lm) * 64);
        short8 bhB = *(const short8*)(W2hi + wbase + (size_t)(1 * 16 + lm) * 64);
        short8 blB = *(const short8*)(W2lo + wbase + (size_t)(1 * 16 + lm) * 64);

        // W1/b1 slices for this ks (k-contiguous 8 elems)
        const float4 w1a = *(const float4*)(W1 + (size_t)c * 64 + ks * 32 + lg * 8);
        const float4 w1b = *(const float4*)(W1 + (size_t)c * 64 + ks * 32 + lg * 8 + 4);
        const float4 b1a = *(const float4*)(b1 + (size_t)c * 64 + ks * 32 + lg * 8);
        const float4 b1b = *(const float4*)(b1 + (size_t)c * 64 + ks * 32 + lg * 8 + 4);
        const float w1r[8] = {w1a.x, w1a.y, w1a.z, w1a.w, w1b.x, w1b.y, w1b.z, w1b.w};
        const float b1r[8] = {b1a.x, b1a.y, b1a.z, b1a.w, b1b.x, b1b.y, b1b.z, b1b.w};

        // A-frags (VALU work overlaps the in-flight B loads)
        short8 afr[4];
        #pragma unroll
        for (int mt = 0; mt < 4; ++mt) {
            Frag8 af;
            #pragma unroll
            for (int j = 0; j < 8; ++j)
                af.s[j] = (short)bfbits(fmaxf(fmaf(sv[mt], w1r[j], b1r[j]), 0.f));
            afr[mt] = af.v;
        }

        // explicit schedule: MFMA(cur) then prefetch(next)
        {
            #pragma unroll
            for (int mt = 0; mt < 4; ++mt)
                acc[mt][0] = __builtin_amdgcn_mfma_f32_16x16x32_bf16(afr[mt], bhA, acc[mt][0], 0, 0, 0);
            #pragma unroll
            for (int mt = 0; mt < 4; ++mt)
                acc[mt][0] = __builtin_amdgcn_mfma_f32_16x16x32_bf16(afr[mt], blA, acc[mt][0], 0, 0, 0);
            bhA = *(const short8*)(W2hi + wbase + (size_t)(2 * 16 + lm) * 64);
            blA = *(const short8*)(W2lo + wbase + (size_t)(2 * 16 + lm) * 64);

            #pragma unroll
            for (int mt = 0; mt < 4; ++mt)
                acc[mt][1] = __builtin_amdgcn_mfma_f32_16x16x32_bf16(afr[mt], bhB, acc[mt][1], 0, 0, 0);
            #pragma unroll
            for (int mt = 0; mt < 4; ++mt)
                acc[mt][1] = __builtin_amdgcn_mfma_f32_16x16x32_bf16(afr[mt], blB, acc[mt][1], 0, 0, 0);
            bhB = *(const short8*)(W2hi + wbase + (size_t)(3 * 16 + lm) * 64);
            blB = *(const short8*)(W2lo + wbase + (size_t)(3 * 16 + lm) * 64);

            #pragma unroll
            for (int mt = 0; mt < 4; ++mt)
                acc[mt][2] = __builtin_amdgcn_mfma_f32_16x16x32_bf16(afr[mt], bhA, acc[mt][2], 0, 0, 0);
            #pragma unroll
            for (int mt = 0; mt < 4; ++mt)
                acc[mt][2] = __builtin_amdgcn_mfma_f32_16x16x32_bf16(afr[mt], blA, acc[mt][2], 0, 0, 0);

            #pragma unroll
            for (int mt = 0; mt < 4; ++mt)
                acc[mt][3] = __builtin_amdgcn_mfma_f32_16x16x32_bf16(afr[mt], bhB, acc[mt][3], 0, 0, 0);
            #pragma unroll
            for (int mt = 0; mt < 4; ++mt)
                acc[mt][3] = __builtin_amdgcn_mfma_f32_16x16x32_bf16(afr[mt], blB, acc[mt][3], 0, 0, 0);
        }
    }

    // add b2, sum of squares over f (lane-local over nt, butterfly over lm lanes)
    float rsc[4][4];
    #pragma unroll
    for (int mt = 0; mt < 4; ++mt)
        #pragma unroll
        for (int i = 0; i < 4; ++i) {
            float s2 = 0.f;
            #pragma unroll
            for (int nt = 0; nt < 4; ++nt) {
                float vv = acc[mt][nt][i] + b2r[nt];
                acc[mt][nt][i] = vv;
                s2 = fmaf(vv, vv, s2);
            }
            s2 += __shfl_xor(s2, 1); s2 += __shfl_xor(s2, 2);
            s2 += __shfl_xor(s2, 4); s2 += __shfl_xor(s2, 8);
            rsc[mt][i] = 1.f / fmaxf(sqrtf(s2), 1e-12f);
        }

    // two 32-row passes: repack into 32KB LDS, then coalesced writeout
    #pragma unroll
    for (int p = 0; p < 2; ++p) {
        if (p) __syncthreads();            // protect previous readout
        #pragma unroll
        for (int mh = 0; mh < 2; ++mh) {
            const int mt = p * 2 + mh;
            #pragma unroll
            for (int i = 0; i < 4; ++i) {
                const int rl = mh * 16 + lg * 4 + i;      // local row 0..31
                const uint32_t rowbase = (uint32_t)rl * 1024u;
                const uint32_t swz = (uint32_t)(rl & 7) << 4;
                #pragma unroll
                for (int nt = 0; nt < 4; ++nt) {
                    const int f = nt * 16 + lm;
                    const uint32_t bo = (rowbase + (uint32_t)f * 16u + (uint32_t)cl * 2u) ^ swz;
                    *(unsigned short*)(sOut + bo) = bfbits(acc[mt][nt][i] * rsc[mt][i]);
                }
            }
        }
        __syncthreads();
        #pragma unroll
        for (int it = 0; it < 4; ++it) {
            const int unit = t + it * 512;
            const int rl = unit >> 6, f = unit & 63;
            const uint32_t lb = ((uint32_t)rl * 1024u + (uint32_t)f * 16u) ^ ((uint32_t)(rl & 7) << 4);
            const uint4 val = *(const uint4*)(sOut + lb);
            ((uint4*)vbuf)[((size_t)(r0 + p * 32 + rl) * 16 + cg) * 64 + f] = val;
        }
    }
}

// ---------- K23: fused ctx + projection ----------
// block = 512 thr (8 waves), 16 rows; 2 column-groups of 64.  LDS 128 KB -> 1 block/CU,
// 2 waves/SIMD  =>  __launch_bounds__(512, 2) gives the full 256-VGPR budget (R8 spilled
// at the default 128-VGPR cap: WRITE_SIZE 151 MB scratch signature).
// phase A (per g): wave computes ctx for 2 rows x 64 c, both rows interleaved
//                  in-register (ks-double-buffered V frags) -> LDS bf16 swizzled.
// phase B (per g): wave projects 8 columns over one 16-row M-tile -> out.
__global__ __launch_bounds__(512, 2) void k23_fused(
        const unsigned short* __restrict__ whi, const unsigned short* __restrict__ wlo,
        const uint32_t* __restrict__ vbuf,
        const unsigned short* __restrict__ P1hi, const unsigned short* __restrict__ P1lo,
        const float* __restrict__ pb1, const float* __restrict__ P2,
        const float* __restrict__ pb2, float* __restrict__ out, int rowOff) {
    __shared__ char sCtx[16 * 64 * 64 * 2];   // 128 KB: [16r][64c][64e] bf16, ^((r^c)&7)<<4
    const int t = threadIdx.x;
    const int lane = t & 63, wv = t >> 6;
    const int lm = lane & 15, lg = lane >> 4;
    const int R0 = blockIdx.x * 16;

    const int rA = wv * 2, rB = wv * 2 + 1;
    const char* vrowA = (const char*)vbuf + ((size_t)(R0 + rA) << 14);
    const char* vrowB = (const char*)vbuf + ((size_t)(R0 + rB) << 14);

#define LDV(VR, KS, ET) (*(const short8*)((VR) + ((KS) * 4 + lg) * 1024 + ((ET) * 16 + lm) * 16))

    #pragma unroll 1
    for (int g = 0; g < 2; ++g) {
        // ---------------- phase A: ctx for rows rA,rB x 64 c ----------------
        f32x4 accA[4][4], accB[4][4];     // [et][mt]
        #pragma unroll
        for (int et = 0; et < 4; ++et)
            #pragma unroll
            for (int mt = 0; mt < 4; ++mt) {
                accA[et][mt] = (f32x4){0.f, 0.f, 0.f, 0.f};
                accB[et][mt] = (f32x4){0.f, 0.f, 0.f, 0.f};
            }

        short8 va[2][4], vb[2][4];        // [buf][et], indices compile-time under unroll
        #pragma unroll
        for (int et = 0; et < 4; ++et) { va[0][et] = LDV(vrowA, 0, et); vb[0][et] = LDV(vrowB, 0, et); }

        #pragma unroll
        for (int ks = 0; ks < 4; ++ks) {
            const int cur = ks & 1, nxt = cur ^ 1;
            if (ks < 3) {
                #pragma unroll
                for (int et = 0; et < 4; ++et) {
                    va[nxt][et] = LDV(vrowA, ks + 1, et);
                    vb[nxt][et] = LDV(vrowB, ks + 1, et);
                }
            }
            #pragma unroll
            for (int mt = 0; mt < 4; ++mt) {
                const size_t wb = (size_t)(g * 64 + mt * 16 + lm) * C_DIM + ks * 32 + lg * 8;
                const short8 bh = *(const short8*)(whi + wb);
                const short8 bl = *(const short8*)(wlo + wb);
                #pragma unroll
                for (int et = 0; et < 4; ++et) {
                    accA[et][mt] = __builtin_amdgcn_mfma_f32_16x16x32_bf16(va[cur][et], bh, accA[et][mt], 0, 0, 0);
                    accA[et][mt] = __builtin_amdgcn_mfma_f32_16x16x32_bf16(va[cur][et], bl, accA[et][mt], 0, 0, 0);
                    accB[et][mt] = __builtin_amdgcn_mfma_f32_16x16x32_bf16(vb[cur][et], bh, accB[et][mt], 0, 0, 0);
                    accB[et][mt] = __builtin_amdgcn_mfma_f32_16x16x32_bf16(vb[cur][et], bl, accB[et][mt], 0, 0, 0);
                }
            }
        }

        // write ctx rows rA,rB into LDS (8 B per (et,mt) per lane), swizzled
        #pragma unroll
        for (int et = 0; et < 4; ++et)
            #pragma unroll
            for (int mt = 0; mt < 4; ++mt) {
                const int cloc = mt * 16 + lm;
                {
                    const uint32_t u0 = (uint32_t)bfbits(accA[et][mt][0]) | ((uint32_t)bfbits(accA[et][mt][1]) << 16);
                    const uint32_t u1 = (uint32_t)bfbits(accA[et][mt][2]) | ((uint32_t)bfbits(accA[et][mt][3]) << 16);
                    uint32_t bo = (uint32_t)rA * 8192u + (uint32_t)cloc * 128u + (uint32_t)(et * 32 + lg * 8);
                    bo ^= (uint32_t)((rA ^ cloc) & 7) << 4;
                    *(uint2*)(sCtx + bo) = make_uint2(u0, u1);
                }
                {
                    const uint32_t u0 = (uint32_t)bfbits(accB[et][mt][0]) | ((uint32_t)bfbits(accB[et][mt][1]) << 16);
                    const uint32_t u1 = (uint32_t)bfbits(accB[et][mt][2]) | ((uint32_t)bfbits(accB[et][mt][3]) << 16);
                    uint32_t bo = (uint32_t)rB * 8192u + (uint32_t)cloc * 128u + (uint32_t)(et * 32 + lg * 8);
                    bo ^= (uint32_t)((rB ^ cloc) & 7) << 4;
                    *(uint2*)(sCtx + bo) = make_uint2(u0, u1);
                }
            }
        __syncthreads();

        // ---------------- phase B: projection for this wave's 8 columns ----------------
        #pragma unroll 1
        for (int cc = 0; cc < 8; ++cc) {
            const int cloc = wv * 8 + cc;          // 0..63 within group
            const int c = g * 64 + cloc;

            float pb1r[4], p2r[4];
            #pragma unroll
            for (int nt = 0; nt < 4; ++nt) {
                pb1r[nt] = pb1[(size_t)c * 64 + nt * 16 + lm];
                p2r[nt]  = P2[(size_t)c * 64 + nt * 16 + lm];
            }
            const float pb2c = pb2[c];

            f32x4 acc2[4];                         // [nt]
            #pragma unroll
            for (int nt = 0; nt < 4; ++nt)
                acc2[nt] = (f32x4){0.f, 0.f, 0.f, 0.f};

            #pragma unroll
            for (int ks = 0; ks < 2; ++ks) {
                short8 a0;
                {
                    uint32_t bo = (uint32_t)lm * 8192u + (uint32_t)cloc * 128u +
                                  (uint32_t)(ks * 64 + lg * 16);
                    bo ^= (uint32_t)((lm ^ cloc) & 7) << 4;
                    a0 = *(const short8*)(sCtx + bo);
                }
                #pragma unroll
                for (int nt = 0; nt < 4; ++nt) {
                    const size_t wb = ((size_t)c * 64 + nt * 16 + lm) * 64 + ks * 32 + lg * 8;
                    const short8 bh = *(const short8*)(P1hi + wb);
                    const short8 bl = *(const short8*)(P1lo + wb);
                    acc2[nt] = __builtin_amdgcn_mfma_f32_16x16x32_bf16(a0, bh, acc2[nt], 0, 0, 0);
                    acc2[nt] = __builtin_amdgcn_mfma_f32_16x16x32_bf16(a0, bl, acc2[nt], 0, 0, 0);
                }
            }

            // epilogue: relu, dot with P2 over f, butterfly over lm, store
            #pragma unroll
            for (int i = 0; i < 4; ++i) {
                float p = 0.f;
                #pragma unroll
                for (int nt = 0; nt < 4; ++nt)
                    p = fmaf(fmaxf(acc2[nt][i] + pb1r[nt], 0.f), p2r[nt], p);
                p += __shfl_xor(p, 1); p += __shfl_xor(p, 2);
                p += __shfl_xor(p, 4); p += __shfl_xor(p, 8);
                if (lm == 0)
                    out[(size_t)(rowOff + R0 + lg * 4 + i) * C_DIM + c] = p + pb2c;
            }
        }
        __syncthreads();
    }
#undef LDV
}

// ---------- host ----------
extern "C" void kernel_launch(void* const* d_in, const int* in_sizes, int n_in,
                              void* d_out, int out_size, void* d_ws, size_t ws_size,
                              hipStream_t stream) {
    const float* samples = (const float*)d_in[0];
    const float* W1  = (const float*)d_in[1];
    const float* b1  = (const float*)d_in[2];
    const float* W2  = (const float*)d_in[3];
    const float* b2  = (const float*)d_in[4];
    const float* q   = (const float*)d_in[5];
    const float* P1  = (const float*)d_in[6];
    const float* pb1 = (const float*)d_in[7];
    const float* P2  = (const float*)d_in[8];
    const float* pb2 = (const float*)d_in[9];
    float* out = (float*)d_out;

    char* ws = (char*)d_ws;
    unsigned short* whi  = (unsigned short*)ws;                       // 32KB
    unsigned short* wlo  = (unsigned short*)(ws + 32768);             // 32KB
    unsigned short* W2hi = (unsigned short*)(ws + 65536);             // 1MB
    unsigned short* W2lo = (unsigned short*)(ws + 65536 + 1048576);   // 1MB
    unsigned short* P1hi = (unsigned short*)(ws + 65536 + 2097152);   // 1MB
    unsigned short* P1lo = (unsigned short*)(ws + 65536 + 3145728);   // 1MB
    const size_t head = 65536 + 4194304;

    // single region: V, 16KB per row
    size_t avail = (ws_size > head) ? ws_size - head : 0;
    long maxRows = (long)(avail / ((size_t)C_DIM * E_DIM * 2));
    maxRows = (maxRows / 256) * 256;
    if (maxRows > B_DIM) maxRows = B_DIM;
    if (maxRows < 256) maxRows = 256;

    uint32_t* vbuf = (uint32_t*)(ws + head);

    k0_softmax<<<dim3(C_DIM), dim3(C_DIM), 0, stream>>>(q, whi, wlo);
    kP_split<<<dim3(512), 256, 0, stream>>>(W2, W2hi, W2lo);   // 524288 floats / 4 / 256
    kP_split<<<dim3(512), 256, 0, stream>>>(P1, P1hi, P1lo);

    for (int off = 0; off < B_DIM; off += (int)maxRows) {
        const int rows = (int)(((long)(B_DIM - off) < maxRows) ? (long)(B_DIM - off) : maxRows);
        k1_value<<<dim3(rows / 64, 16), 512, 0, stream>>>(samples, W1, b1, W2hi, W2lo, b2, vbuf, off);
        k23_fused<<<dim3(rows / 16), 512, 0, stream>>>(whi, wlo, vbuf, P1hi, P1lo, pb1, P2, pb2, out, off);
    }
}

// Round 11
// 244.471 us; speedup vs baseline: 2.4379x; 1.4450x over previous
//
#include <hip/hip_runtime.h>
#include <hip/hip_bf16.h>
#include <cstdint>

#define C_DIM 128
#define E_DIM 64
#define B_DIM 8192

typedef __attribute__((ext_vector_type(8))) short short8;
typedef __attribute__((ext_vector_type(4))) float f32x4;

union Frag8 { short8 v; short s[8]; uint32_t u[4]; };

__device__ __forceinline__ unsigned short bfbits(float x) {
    union { __hip_bfloat16 h; unsigned short u; } cv;
    cv.h = __float2bfloat16(x);
    return cv.u;
}
__device__ __forceinline__ float bits2f(unsigned short b) {
    return __uint_as_float(((uint32_t)b) << 16);
}

// ---------- K0: w = softmax(q,axis=1), zero diag, split hi/lo bf16, layout [c][n] ----------
__global__ __launch_bounds__(128) void k0_softmax(const float* __restrict__ q,
                                                  unsigned short* __restrict__ whi,
                                                  unsigned short* __restrict__ wlo) {
    const int c = blockIdx.x;
    const int t = threadIdx.x;            // n
    __shared__ float redM[2], redS[2];
    float v = q[c * C_DIM + t];
    float m = v;
    #pragma unroll
    for (int o = 32; o > 0; o >>= 1) m = fmaxf(m, __shfl_xor(m, o));
    if ((t & 63) == 0) redM[t >> 6] = m;
    __syncthreads();
    m = fmaxf(redM[0], redM[1]);
    float e = expf(v - m);
    float s = e;
    #pragma unroll
    for (int o = 32; o > 0; o >>= 1) s += __shfl_xor(s, o);
    if ((t & 63) == 0) redS[t >> 6] = s;
    __syncthreads();
    s = redS[0] + redS[1];
    float w = e / s;
    if (t == c) w = 0.f;                  // zero diagonal AFTER softmax
    unsigned short hb = bfbits(w);
    whi[c * C_DIM + t] = hb;
    wlo[c * C_DIM + t] = bfbits(w - bits2f(hb));
}

// ---------- KP: elementwise hi/lo bf16 split of a f32 weight tensor ----------
__global__ __launch_bounds__(256) void kP_split(const float* __restrict__ src,
                                                unsigned short* __restrict__ hi,
                                                unsigned short* __restrict__ lo) {
    const int i = blockIdx.x * 256 + threadIdx.x;   // index in float4 units
    const float4 v = ((const float4*)src)[i];
    float f[4] = {v.x, v.y, v.z, v.w};
    unsigned short h[4], l[4];
    #pragma unroll
    for (int j = 0; j < 4; ++j) {
        h[j] = bfbits(f[j]);
        l[j] = bfbits(f[j] - bits2f(h[j]));
    }
    ((ushort4*)hi)[i] = make_ushort4(h[0], h[1], h[2], h[3]);
    ((ushort4*)lo)[i] = make_ushort4(l[0], l[1], l[2], l[3]);
}

// ---------- K1: value MLP + L2 norm, MFMA. Output V[r][n8][e][8n] bf16 ----------
// block = 64 rows x 8 columns, 8 waves (1 column each). D: m=r, n=f.
__global__ __launch_bounds__(512, 4) void k1_value(
        const float* __restrict__ samples, const float* __restrict__ W1,
        const float* __restrict__ b1, const unsigned short* __restrict__ W2hi,
        const unsigned short* __restrict__ W2lo, const float* __restrict__ b2,
        uint32_t* __restrict__ vbuf, int rowOff) {
    __shared__ char sOut[32 * 1024];       // [r32][f][c_local] bf16, XOR-swizzled
    const int t = threadIdx.x;
    const int rt = blockIdx.x, cg = blockIdx.y;
    const int r0 = rt * 64;
    const int cl = t >> 6;                 // wave = local column
    const int lane = t & 63;
    const int lm = lane & 15, lg = lane >> 4;
    const int c = cg * 8 + cl;

    // scatter sample loads issued first (deepest latency)
    float sv[4];
    #pragma unroll
    for (int mt = 0; mt < 4; ++mt)
        sv[mt] = samples[(size_t)(rowOff + r0 + mt * 16 + lm) * C_DIM + c];

    float b2r[4];
    #pragma unroll
    for (int nt = 0; nt < 4; ++nt) b2r[nt] = b2[(size_t)c * 64 + nt * 16 + lm];

    f32x4 acc[4][4];
    #pragma unroll
    for (int mt = 0; mt < 4; ++mt)
        #pragma unroll
        for (int nt = 0; nt < 4; ++nt)
            acc[mt][nt] = (f32x4){0.f, 0.f, 0.f, 0.f};

    #pragma unroll
    for (int ks = 0; ks < 2; ++ks) {
        const size_t wbase = ((size_t)c * 64) * 64 + ks * 32 + lg * 8;

        // rotating double-buffer of B-frag pairs (static names, rule #20)
        short8 bhA = *(const short8*)(W2hi + wbase + (size_t)(0 * 16 + lm) * 64);
        short8 blA = *(const short8*)(W2lo + wbase + (size_t)(0 * 16 + lm) * 64);
        short8 bhB = *(const short8*)(W2hi + wbase + (size_t)(1 * 16 + lm) * 64);
        short8 blB = *(const short8*)(W2lo + wbase + (size_t)(1 * 16 + lm) * 64);

        // W1/b1 slices for this ks (k-contiguous 8 elems)
        const float4 w1a = *(const float4*)(W1 + (size_t)c * 64 + ks * 32 + lg * 8);
        const float4 w1b = *(const float4*)(W1 + (size_t)c * 64 + ks * 32 + lg * 8 + 4);
        const float4 b1a = *(const float4*)(b1 + (size_t)c * 64 + ks * 32 + lg * 8);
        const float4 b1b = *(const float4*)(b1 + (size_t)c * 64 + ks * 32 + lg * 8 + 4);
        const float w1r[8] = {w1a.x, w1a.y, w1a.z, w1a.w, w1b.x, w1b.y, w1b.z, w1b.w};
        const float b1r[8] = {b1a.x, b1a.y, b1a.z, b1a.w, b1b.x, b1b.y, b1b.z, b1b.w};

        // A-frags (VALU work overlaps the in-flight B loads)
        short8 afr[4];
        #pragma unroll
        for (int mt = 0; mt < 4; ++mt) {
            Frag8 af;
            #pragma unroll
            for (int j = 0; j < 8; ++j)
                af.s[j] = (short)bfbits(fmaxf(fmaf(sv[mt], w1r[j], b1r[j]), 0.f));
            afr[mt] = af.v;
        }

        // explicit schedule: MFMA(cur) then prefetch(next)
        {
            #pragma unroll
            for (int mt = 0; mt < 4; ++mt)
                acc[mt][0] = __builtin_amdgcn_mfma_f32_16x16x32_bf16(afr[mt], bhA, acc[mt][0], 0, 0, 0);
            #pragma unroll
            for (int mt = 0; mt < 4; ++mt)
                acc[mt][0] = __builtin_amdgcn_mfma_f32_16x16x32_bf16(afr[mt], blA, acc[mt][0], 0, 0, 0);
            bhA = *(const short8*)(W2hi + wbase + (size_t)(2 * 16 + lm) * 64);
            blA = *(const short8*)(W2lo + wbase + (size_t)(2 * 16 + lm) * 64);

            #pragma unroll
            for (int mt = 0; mt < 4; ++mt)
                acc[mt][1] = __builtin_amdgcn_mfma_f32_16x16x32_bf16(afr[mt], bhB, acc[mt][1], 0, 0, 0);
            #pragma unroll
            for (int mt = 0; mt < 4; ++mt)
                acc[mt][1] = __builtin_amdgcn_mfma_f32_16x16x32_bf16(afr[mt], blB, acc[mt][1], 0, 0, 0);
            bhB = *(const short8*)(W2hi + wbase + (size_t)(3 * 16 + lm) * 64);
            blB = *(const short8*)(W2lo + wbase + (size_t)(3 * 16 + lm) * 64);

            #pragma unroll
            for (int mt = 0; mt < 4; ++mt)
                acc[mt][2] = __builtin_amdgcn_mfma_f32_16x16x32_bf16(afr[mt], bhA, acc[mt][2], 0, 0, 0);
            #pragma unroll
            for (int mt = 0; mt < 4; ++mt)
                acc[mt][2] = __builtin_amdgcn_mfma_f32_16x16x32_bf16(afr[mt], blA, acc[mt][2], 0, 0, 0);

            #pragma unroll
            for (int mt = 0; mt < 4; ++mt)
                acc[mt][3] = __builtin_amdgcn_mfma_f32_16x16x32_bf16(afr[mt], bhB, acc[mt][3], 0, 0, 0);
            #pragma unroll
            for (int mt = 0; mt < 4; ++mt)
                acc[mt][3] = __builtin_amdgcn_mfma_f32_16x16x32_bf16(afr[mt], blB, acc[mt][3], 0, 0, 0);
        }
    }

    // add b2, sum of squares over f (lane-local over nt, butterfly over lm lanes)
    float rsc[4][4];
    #pragma unroll
    for (int mt = 0; mt < 4; ++mt)
        #pragma unroll
        for (int i = 0; i < 4; ++i) {
            float s2 = 0.f;
            #pragma unroll
            for (int nt = 0; nt < 4; ++nt) {
                float vv = acc[mt][nt][i] + b2r[nt];
                acc[mt][nt][i] = vv;
                s2 = fmaf(vv, vv, s2);
            }
            s2 += __shfl_xor(s2, 1); s2 += __shfl_xor(s2, 2);
            s2 += __shfl_xor(s2, 4); s2 += __shfl_xor(s2, 8);
            rsc[mt][i] = 1.f / fmaxf(sqrtf(s2), 1e-12f);
        }

    // two 32-row passes: repack into 32KB LDS, then coalesced writeout
    #pragma unroll
    for (int p = 0; p < 2; ++p) {
        if (p) __syncthreads();            // protect previous readout
        #pragma unroll
        for (int mh = 0; mh < 2; ++mh) {
            const int mt = p * 2 + mh;
            #pragma unroll
            for (int i = 0; i < 4; ++i) {
                const int rl = mh * 16 + lg * 4 + i;      // local row 0..31
                const uint32_t rowbase = (uint32_t)rl * 1024u;
                const uint32_t swz = (uint32_t)(rl & 7) << 4;
                #pragma unroll
                for (int nt = 0; nt < 4; ++nt) {
                    const int f = nt * 16 + lm;
                    const uint32_t bo = (rowbase + (uint32_t)f * 16u + (uint32_t)cl * 2u) ^ swz;
                    *(unsigned short*)(sOut + bo) = bfbits(acc[mt][nt][i] * rsc[mt][i]);
                }
            }
        }
        __syncthreads();
        #pragma unroll
        for (int it = 0; it < 4; ++it) {
            const int unit = t + it * 512;
            const int rl = unit >> 6, f = unit & 63;
            const uint32_t lb = ((uint32_t)rl * 1024u + (uint32_t)f * 16u) ^ ((uint32_t)(rl & 7) << 4);
            const uint4 val = *(const uint4*)(sOut + lb);
            ((uint4*)vbuf)[((size_t)(r0 + p * 32 + rl) * 16 + cg) * 64 + f] = val;
        }
    }
}

// ---------- K23: fused ctx + projection (R6 geometry, re-budgeted registers) ----------
// block = 512 thr (8 waves), 32 rows; 4 column-groups of 32. LDS 128 KB.
// phase A (per g): wave computes ctx for its 4 rows as 2 row-PAIRS interleaved
//   in-register; w = single bf16 (hi only) -> 32 fewer VGPRs, half the MFMAs;
//   V frags ks-double-buffered per pair (8 loads in flight). acc fits AGPRs.
// phase B (per g): wave projects 4 columns, 2 M-tiles (verbatim from R6, P1 hi/lo).
__global__ __launch_bounds__(512) void k23_fused(
        const unsigned short* __restrict__ whi,
        const uint32_t* __restrict__ vbuf,
        const unsigned short* __restrict__ P1hi, const unsigned short* __restrict__ P1lo,
        const float* __restrict__ pb1, const float* __restrict__ P2,
        const float* __restrict__ pb2, float* __restrict__ out, int rowOff) {
    __shared__ char sCtx[32 * 32 * 64 * 2];   // 128 KB: [32r][32c][64e] bf16, ^((r^c)&7)<<4
    const int t = threadIdx.x;
    const int lane = t & 63, wv = t >> 6;
    const int lm = lane & 15, lg = lane >> 4;
    const int R0 = blockIdx.x * 32;

#define LDV(VR, KS, ET) (*(const short8*)((VR) + ((KS) * 4 + lg) * 1024 + ((ET) * 16 + lm) * 16))

    #pragma unroll 1
    for (int g = 0; g < 4; ++g) {
        // hoist w B-frags for this g (hi only), straight from L2: 8 short8 = 32 VGPR
        short8 wh[2][4];
        #pragma unroll
        for (int mt = 0; mt < 2; ++mt)
            #pragma unroll
            for (int ks = 0; ks < 4; ++ks)
                wh[mt][ks] = *(const short8*)(whi +
                    (size_t)(g * 32 + mt * 16 + lm) * C_DIM + ks * 32 + lg * 8);

        // ---------------- phase A: 2 row-pairs, interleaved in-register ----------------
        #pragma unroll 1
        for (int pp = 0; pp < 2; ++pp) {
            const int rA = wv * 4 + pp * 2, rB = rA + 1;
            const char* vrowA = (const char*)vbuf + ((size_t)(R0 + rA) << 14);
            const char* vrowB = (const char*)vbuf + ((size_t)(R0 + rB) << 14);

            f32x4 accA[4][2], accB[4][2];      // [et][mt] -> AGPRs
            #pragma unroll
            for (int et = 0; et < 4; ++et)
                #pragma unroll
                for (int mt = 0; mt < 2; ++mt) {
                    accA[et][mt] = (f32x4){0.f, 0.f, 0.f, 0.f};
                    accB[et][mt] = (f32x4){0.f, 0.f, 0.f, 0.f};
                }

            short8 vaX[4], vaY[4], vbX[4], vbY[4];   // double buffers, static under unroll
            #pragma unroll
            for (int et = 0; et < 4; ++et) { vaX[et] = LDV(vrowA, 0, et); vbX[et] = LDV(vrowB, 0, et); }

#define PAIR_STEP(KS, CA, CB, NA, NB, PF)                                                  \
            {                                                                              \
                if (PF) {                                                                  \
                    _Pragma("unroll")                                                      \
                    for (int et = 0; et < 4; ++et) {                                       \
                        NA[et] = LDV(vrowA, (KS) + 1, et);                                 \
                        NB[et] = LDV(vrowB, (KS) + 1, et);                                 \
                    }                                                                      \
                }                                                                          \
                _Pragma("unroll")                                                          \
                for (int mt = 0; mt < 2; ++mt) {                                           \
                    const short8 bh = wh[mt][KS];                                          \
                    _Pragma("unroll")                                                      \
                    for (int et = 0; et < 4; ++et) {                                       \
                        accA[et][mt] = __builtin_amdgcn_mfma_f32_16x16x32_bf16(CA[et], bh, \
                                                                 accA[et][mt], 0, 0, 0);   \
                        accB[et][mt] = __builtin_amdgcn_mfma_f32_16x16x32_bf16(CB[et], bh, \
                                                                 accB[et][mt], 0, 0, 0);   \
                    }                                                                      \
                }                                                                          \
            }
            PAIR_STEP(0, vaX, vbX, vaY, vbY, 1)
            PAIR_STEP(1, vaY, vbY, vaX, vbX, 1)
            PAIR_STEP(2, vaX, vbX, vaY, vbY, 1)
            PAIR_STEP(3, vaY, vbY, vaX, vbX, 0)
#undef PAIR_STEP

            // write ctx rows rA,rB into LDS (8 B per (et,mt) per lane), swizzled
            #pragma unroll
            for (int et = 0; et < 4; ++et)
                #pragma unroll
                for (int mt = 0; mt < 2; ++mt) {
                    const int cloc = mt * 16 + lm;
                    {
                        const uint32_t u0 = (uint32_t)bfbits(accA[et][mt][0]) | ((uint32_t)bfbits(accA[et][mt][1]) << 16);
                        const uint32_t u1 = (uint32_t)bfbits(accA[et][mt][2]) | ((uint32_t)bfbits(accA[et][mt][3]) << 16);
                        uint32_t bo = (uint32_t)rA * 4096u + (uint32_t)cloc * 128u + (uint32_t)(et * 32 + lg * 8);
                        bo ^= (uint32_t)((rA ^ cloc) & 7) << 4;
                        *(uint2*)(sCtx + bo) = make_uint2(u0, u1);
                    }
                    {
                        const uint32_t u0 = (uint32_t)bfbits(accB[et][mt][0]) | ((uint32_t)bfbits(accB[et][mt][1]) << 16);
                        const uint32_t u1 = (uint32_t)bfbits(accB[et][mt][2]) | ((uint32_t)bfbits(accB[et][mt][3]) << 16);
                        uint32_t bo = (uint32_t)rB * 4096u + (uint32_t)cloc * 128u + (uint32_t)(et * 32 + lg * 8);
                        bo ^= (uint32_t)((rB ^ cloc) & 7) << 4;
                        *(uint2*)(sCtx + bo) = make_uint2(u0, u1);
                    }
                }
        }
        __syncthreads();

        // ---------------- phase B: projection for this wave's 4 columns ----------------
        #pragma unroll 1
        for (int cc = 0; cc < 4; ++cc) {
            const int cloc = wv * 4 + cc;          // 0..31 within group
            const int c = g * 32 + cloc;

            float pb1r[4], p2r[4];
            #pragma unroll
            for (int nt = 0; nt < 4; ++nt) {
                pb1r[nt] = pb1[(size_t)c * 64 + nt * 16 + lm];
                p2r[nt]  = P2[(size_t)c * 64 + nt * 16 + lm];
            }
            const float pb2c = pb2[c];

            f32x4 acc2[2][4];                      // [mt2][nt]
            #pragma unroll
            for (int mt2 = 0; mt2 < 2; ++mt2)
                #pragma unroll
                for (int nt = 0; nt < 4; ++nt)
                    acc2[mt2][nt] = (f32x4){0.f, 0.f, 0.f, 0.f};

            #pragma unroll
            for (int ks = 0; ks < 2; ++ks) {
                short8 a0, a1;
                {
                    const int rl0 = 0 * 16 + lm;
                    uint32_t bo = (uint32_t)rl0 * 4096u + (uint32_t)cloc * 128u +
                                  (uint32_t)(ks * 64 + lg * 16);
                    bo ^= (uint32_t)((rl0 ^ cloc) & 7) << 4;
                    a0 = *(const short8*)(sCtx + bo);
                }
                {
                    const int rl1 = 1 * 16 + lm;
                    uint32_t bo = (uint32_t)rl1 * 4096u + (uint32_t)cloc * 128u +
                                  (uint32_t)(ks * 64 + lg * 16);
                    bo ^= (uint32_t)((rl1 ^ cloc) & 7) << 4;
                    a1 = *(const short8*)(sCtx + bo);
                }
                #pragma unroll
                for (int nt = 0; nt < 4; ++nt) {
                    const size_t wb = ((size_t)c * 64 + nt * 16 + lm) * 64 + ks * 32 + lg * 8;
                    const short8 bh = *(const short8*)(P1hi + wb);
                    const short8 bl = *(const short8*)(P1lo + wb);
                    acc2[0][nt] = __builtin_amdgcn_mfma_f32_16x16x32_bf16(a0, bh, acc2[0][nt], 0, 0, 0);
                    acc2[0][nt] = __builtin_amdgcn_mfma_f32_16x16x32_bf16(a0, bl, acc2[0][nt], 0, 0, 0);
                    acc2[1][nt] = __builtin_amdgcn_mfma_f32_16x16x32_bf16(a1, bh, acc2[1][nt], 0, 0, 0);
                    acc2[1][nt] = __builtin_amdgcn_mfma_f32_16x16x32_bf16(a1, bl, acc2[1][nt], 0, 0, 0);
                }
            }

            // epilogue: relu, dot with P2 over f, butterfly over lm, store
            #pragma unroll
            for (int mt2 = 0; mt2 < 2; ++mt2)
                #pragma unroll
                for (int i = 0; i < 4; ++i) {
                    float p = 0.f;
                    #pragma unroll
                    for (int nt = 0; nt < 4; ++nt)
                        p = fmaf(fmaxf(acc2[mt2][nt][i] + pb1r[nt], 0.f), p2r[nt], p);
                    p += __shfl_xor(p, 1); p += __shfl_xor(p, 2);
                    p += __shfl_xor(p, 4); p += __shfl_xor(p, 8);
                    if (lm == 0)
                        out[(size_t)(rowOff + R0 + mt2 * 16 + lg * 4 + i) * C_DIM + c] = p + pb2c;
                }
        }
        __syncthreads();
    }
#undef LDV
}

// ---------- host ----------
extern "C" void kernel_launch(void* const* d_in, const int* in_sizes, int n_in,
                              void* d_out, int out_size, void* d_ws, size_t ws_size,
                              hipStream_t stream) {
    const float* samples = (const float*)d_in[0];
    const float* W1  = (const float*)d_in[1];
    const float* b1  = (const float*)d_in[2];
    const float* W2  = (const float*)d_in[3];
    const float* b2  = (const float*)d_in[4];
    const float* q   = (const float*)d_in[5];
    const float* P1  = (const float*)d_in[6];
    const float* pb1 = (const float*)d_in[7];
    const float* P2  = (const float*)d_in[8];
    const float* pb2 = (const float*)d_in[9];
    float* out = (float*)d_out;

    char* ws = (char*)d_ws;
    unsigned short* whi  = (unsigned short*)ws;                       // 32KB
    unsigned short* wlo  = (unsigned short*)(ws + 32768);             // 32KB (unused by k23 now)
    unsigned short* W2hi = (unsigned short*)(ws + 65536);             // 1MB
    unsigned short* W2lo = (unsigned short*)(ws + 65536 + 1048576);   // 1MB
    unsigned short* P1hi = (unsigned short*)(ws + 65536 + 2097152);   // 1MB
    unsigned short* P1lo = (unsigned short*)(ws + 65536 + 3145728);   // 1MB
    const size_t head = 65536 + 4194304;

    // single region: V, 16KB per row
    size_t avail = (ws_size > head) ? ws_size - head : 0;
    long maxRows = (long)(avail / ((size_t)C_DIM * E_DIM * 2));
    maxRows = (maxRows / 256) * 256;
    if (maxRows > B_DIM) maxRows = B_DIM;
    if (maxRows < 256) maxRows = 256;

    uint32_t* vbuf = (uint32_t*)(ws + head);

    k0_softmax<<<dim3(C_DIM), dim3(C_DIM), 0, stream>>>(q, whi, wlo);
    kP_split<<<dim3(512), 256, 0, stream>>>(W2, W2hi, W2lo);   // 524288 floats / 4 / 256
    kP_split<<<dim3(512), 256, 0, stream>>>(P1, P1hi, P1lo);

    for (int off = 0; off < B_DIM; off += (int)maxRows) {
        const int rows = (int)(((long)(B_DIM - off) < maxRows) ? (long)(B_DIM - off) : maxRows);
        k1_value<<<dim3(rows / 64, 16), 512, 0, stream>>>(samples, W1, b1, W2hi, W2lo, b2, vbuf, off);
        k23_fused<<<dim3(rows / 32), 512, 0, stream>>>(whi, vbuf, P1hi, P1lo, pb1, P2, pb2, out, off);
    }
}

// Round 12
// 244.263 us; speedup vs baseline: 2.4400x; 1.0009x over previous
//
#include <hip/hip_runtime.h>
#include <hip/hip_bf16.h>
#include <cstdint>

#define C_DIM 128
#define E_DIM 64
#define B_DIM 8192

typedef __attribute__((ext_vector_type(8))) short short8;
typedef __attribute__((ext_vector_type(4))) float f32x4;

union Frag8 { short8 v; short s[8]; uint32_t u[4]; };

__device__ __forceinline__ unsigned short bfbits(float x) {
    union { __hip_bfloat16 h; unsigned short u; } cv;
    cv.h = __float2bfloat16(x);
    return cv.u;
}
__device__ __forceinline__ float bits2f(unsigned short b) {
    return __uint_as_float(((uint32_t)b) << 16);
}

// ---------- K0: w = softmax(q,axis=1), zero diag, split hi/lo bf16, layout [c][n] ----------
__global__ __launch_bounds__(128) void k0_softmax(const float* __restrict__ q,
                                                  unsigned short* __restrict__ whi,
                                                  unsigned short* __restrict__ wlo) {
    const int c = blockIdx.x;
    const int t = threadIdx.x;            // n
    __shared__ float redM[2], redS[2];
    float v = q[c * C_DIM + t];
    float m = v;
    #pragma unroll
    for (int o = 32; o > 0; o >>= 1) m = fmaxf(m, __shfl_xor(m, o));
    if ((t & 63) == 0) redM[t >> 6] = m;
    __syncthreads();
    m = fmaxf(redM[0], redM[1]);
    float e = expf(v - m);
    float s = e;
    #pragma unroll
    for (int o = 32; o > 0; o >>= 1) s += __shfl_xor(s, o);
    if ((t & 63) == 0) redS[t >> 6] = s;
    __syncthreads();
    s = redS[0] + redS[1];
    float w = e / s;
    if (t == c) w = 0.f;                  // zero diagonal AFTER softmax
    unsigned short hb = bfbits(w);
    whi[c * C_DIM + t] = hb;
    wlo[c * C_DIM + t] = bfbits(w - bits2f(hb));
}

// ---------- KP: elementwise hi/lo bf16 split of a f32 weight tensor ----------
__global__ __launch_bounds__(256) void kP_split(const float* __restrict__ src,
                                                unsigned short* __restrict__ hi,
                                                unsigned short* __restrict__ lo) {
    const int i = blockIdx.x * 256 + threadIdx.x;   // index in float4 units
    const float4 v = ((const float4*)src)[i];
    float f[4] = {v.x, v.y, v.z, v.w};
    unsigned short h[4], l[4];
    #pragma unroll
    for (int j = 0; j < 4; ++j) {
        h[j] = bfbits(f[j]);
        l[j] = bfbits(f[j] - bits2f(h[j]));
    }
    ((ushort4*)hi)[i] = make_ushort4(h[0], h[1], h[2], h[3]);
    ((ushort4*)lo)[i] = make_ushort4(l[0], l[1], l[2], l[3]);
}

// ---------- K1: value MLP + L2 norm, MFMA. Output V[r][n8][e][8n] bf16 ----------
// block = 64 rows x 8 columns, 8 waves (1 column each). D: m=r, n=f.
__global__ __launch_bounds__(512, 4) void k1_value(
        const float* __restrict__ samples, const float* __restrict__ W1,
        const float* __restrict__ b1, const unsigned short* __restrict__ W2hi,
        const unsigned short* __restrict__ W2lo, const float* __restrict__ b2,
        uint32_t* __restrict__ vbuf, int rowOff) {
    __shared__ char sOut[32 * 1024];       // [r32][f][c_local] bf16, XOR-swizzled
    const int t = threadIdx.x;
    const int rt = blockIdx.x, cg = blockIdx.y;
    const int r0 = rt * 64;
    const int cl = t >> 6;                 // wave = local column
    const int lane = t & 63;
    const int lm = lane & 15, lg = lane >> 4;
    const int c = cg * 8 + cl;

    // scatter sample loads issued first (deepest latency)
    float sv[4];
    #pragma unroll
    for (int mt = 0; mt < 4; ++mt)
        sv[mt] = samples[(size_t)(rowOff + r0 + mt * 16 + lm) * C_DIM + c];

    float b2r[4];
    #pragma unroll
    for (int nt = 0; nt < 4; ++nt) b2r[nt] = b2[(size_t)c * 64 + nt * 16 + lm];

    f32x4 acc[4][4];
    #pragma unroll
    for (int mt = 0; mt < 4; ++mt)
        #pragma unroll
        for (int nt = 0; nt < 4; ++nt)
            acc[mt][nt] = (f32x4){0.f, 0.f, 0.f, 0.f};

    #pragma unroll
    for (int ks = 0; ks < 2; ++ks) {
        const size_t wbase = ((size_t)c * 64) * 64 + ks * 32 + lg * 8;

        // rotating double-buffer of B-frag pairs (static names, rule #20)
        short8 bhA = *(const short8*)(W2hi + wbase + (size_t)(0 * 16 + lm) * 64);
        short8 blA = *(const short8*)(W2lo + wbase + (size_t)(0 * 16 + lm) * 64);
        short8 bhB = *(const short8*)(W2hi + wbase + (size_t)(1 * 16 + lm) * 64);
        short8 blB = *(const short8*)(W2lo + wbase + (size_t)(1 * 16 + lm) * 64);

        // W1/b1 slices for this ks (k-contiguous 8 elems)
        const float4 w1a = *(const float4*)(W1 + (size_t)c * 64 + ks * 32 + lg * 8);
        const float4 w1b = *(const float4*)(W1 + (size_t)c * 64 + ks * 32 + lg * 8 + 4);
        const float4 b1a = *(const float4*)(b1 + (size_t)c * 64 + ks * 32 + lg * 8);
        const float4 b1b = *(const float4*)(b1 + (size_t)c * 64 + ks * 32 + lg * 8 + 4);
        const float w1r[8] = {w1a.x, w1a.y, w1a.z, w1a.w, w1b.x, w1b.y, w1b.z, w1b.w};
        const float b1r[8] = {b1a.x, b1a.y, b1a.z, b1a.w, b1b.x, b1b.y, b1b.z, b1b.w};

        // A-frags (VALU work overlaps the in-flight B loads)
        short8 afr[4];
        #pragma unroll
        for (int mt = 0; mt < 4; ++mt) {
            Frag8 af;
            #pragma unroll
            for (int j = 0; j < 8; ++j)
                af.s[j] = (short)bfbits(fmaxf(fmaf(sv[mt], w1r[j], b1r[j]), 0.f));
            afr[mt] = af.v;
        }

        // explicit schedule: MFMA(cur) then prefetch(next)
        {
            #pragma unroll
            for (int mt = 0; mt < 4; ++mt)
                acc[mt][0] = __builtin_amdgcn_mfma_f32_16x16x32_bf16(afr[mt], bhA, acc[mt][0], 0, 0, 0);
            #pragma unroll
            for (int mt = 0; mt < 4; ++mt)
                acc[mt][0] = __builtin_amdgcn_mfma_f32_16x16x32_bf16(afr[mt], blA, acc[mt][0], 0, 0, 0);
            bhA = *(const short8*)(W2hi + wbase + (size_t)(2 * 16 + lm) * 64);
            blA = *(const short8*)(W2lo + wbase + (size_t)(2 * 16 + lm) * 64);

            #pragma unroll
            for (int mt = 0; mt < 4; ++mt)
                acc[mt][1] = __builtin_amdgcn_mfma_f32_16x16x32_bf16(afr[mt], bhB, acc[mt][1], 0, 0, 0);
            #pragma unroll
            for (int mt = 0; mt < 4; ++mt)
                acc[mt][1] = __builtin_amdgcn_mfma_f32_16x16x32_bf16(afr[mt], blB, acc[mt][1], 0, 0, 0);
            bhB = *(const short8*)(W2hi + wbase + (size_t)(3 * 16 + lm) * 64);
            blB = *(const short8*)(W2lo + wbase + (size_t)(3 * 16 + lm) * 64);

            #pragma unroll
            for (int mt = 0; mt < 4; ++mt)
                acc[mt][2] = __builtin_amdgcn_mfma_f32_16x16x32_bf16(afr[mt], bhA, acc[mt][2], 0, 0, 0);
            #pragma unroll
            for (int mt = 0; mt < 4; ++mt)
                acc[mt][2] = __builtin_amdgcn_mfma_f32_16x16x32_bf16(afr[mt], blA, acc[mt][2], 0, 0, 0);

            #pragma unroll
            for (int mt = 0; mt < 4; ++mt)
                acc[mt][3] = __builtin_amdgcn_mfma_f32_16x16x32_bf16(afr[mt], bhB, acc[mt][3], 0, 0, 0);
            #pragma unroll
            for (int mt = 0; mt < 4; ++mt)
                acc[mt][3] = __builtin_amdgcn_mfma_f32_16x16x32_bf16(afr[mt], blB, acc[mt][3], 0, 0, 0);
        }
    }

    // add b2, sum of squares over f (lane-local over nt, butterfly over lm lanes)
    float rsc[4][4];
    #pragma unroll
    for (int mt = 0; mt < 4; ++mt)
        #pragma unroll
        for (int i = 0; i < 4; ++i) {
            float s2 = 0.f;
            #pragma unroll
            for (int nt = 0; nt < 4; ++nt) {
                float vv = acc[mt][nt][i] + b2r[nt];
                acc[mt][nt][i] = vv;
                s2 = fmaf(vv, vv, s2);
            }
            s2 += __shfl_xor(s2, 1); s2 += __shfl_xor(s2, 2);
            s2 += __shfl_xor(s2, 4); s2 += __shfl_xor(s2, 8);
            rsc[mt][i] = 1.f / fmaxf(sqrtf(s2), 1e-12f);
        }

    // two 32-row passes: repack into 32KB LDS, then coalesced writeout
    #pragma unroll
    for (int p = 0; p < 2; ++p) {
        if (p) __syncthreads();            // protect previous readout
        #pragma unroll
        for (int mh = 0; mh < 2; ++mh) {
            const int mt = p * 2 + mh;
            #pragma unroll
            for (int i = 0; i < 4; ++i) {
                const int rl = mh * 16 + lg * 4 + i;      // local row 0..31
                const uint32_t rowbase = (uint32_t)rl * 1024u;
                const uint32_t swz = (uint32_t)(rl & 7) << 4;
                #pragma unroll
                for (int nt = 0; nt < 4; ++nt) {
                    const int f = nt * 16 + lm;
                    const uint32_t bo = (rowbase + (uint32_t)f * 16u + (uint32_t)cl * 2u) ^ swz;
                    *(unsigned short*)(sOut + bo) = bfbits(acc[mt][nt][i] * rsc[mt][i]);
                }
            }
        }
        __syncthreads();
        #pragma unroll
        for (int it = 0; it < 4; ++it) {
            const int unit = t + it * 512;
            const int rl = unit >> 6, f = unit & 63;
            const uint32_t lb = ((uint32_t)rl * 1024u + (uint32_t)f * 16u) ^ ((uint32_t)(rl & 7) << 4);
            const uint4 val = *(const uint4*)(sOut + lb);
            ((uint4*)vbuf)[((size_t)(r0 + p * 32 + rl) * 16 + cg) * 64 + f] = val;
        }
    }
}

// ---------- K2: ctx GEMM, V read EXACTLY ONCE (full N=128 per wave) ----------
// block = 256 thr (4 waves), 4 rows; wave = 1 row, acc[4 et][8 nt] in AGPRs.
// A-frags rotating (2 ks live), w single-bf16 rotating from L2.
// ctx staged in 64 KB LDS (c-swizzled) -> coalesced global write (no 2x amp).
__global__ __launch_bounds__(256) void k2_ctx(
        const unsigned short* __restrict__ whi,
        const uint32_t* __restrict__ vbuf, uint32_t* __restrict__ cbuf) {
    __shared__ char sC[65536];             // 4 rows x 16 KB
    const int t = threadIdx.x;
    const int lane = t & 63, wv = t >> 6;
    const int lm = lane & 15, lg = lane >> 4;
    const size_t rbase = (size_t)blockIdx.x * 4;
    const size_t r = rbase + wv;
    const char* vrow = (const char*)vbuf + (r << 14);

#define LDA(KS, ET) (*(const short8*)(vrow + ((KS) * 4 + lg) * 1024 + ((ET) * 16 + lm) * 16))
#define LDW(KS, NT) (*(const short8*)(whi + (size_t)((NT) * 16 + lm) * C_DIM + (KS) * 32 + lg * 8))

    f32x4 acc[4][8];                       // [et][nt] -> AGPRs
    #pragma unroll
    for (int et = 0; et < 4; ++et)
        #pragma unroll
        for (int nt = 0; nt < 8; ++nt)
            acc[et][nt] = (f32x4){0.f, 0.f, 0.f, 0.f};

    // rotating buffers (static names under full unroll)
    short8 afX[4], afY[4], w0[8], w1[8];
    #pragma unroll
    for (int et = 0; et < 4; ++et) afX[et] = LDA(0, et);
    #pragma unroll
    for (int et = 0; et < 4; ++et) afY[et] = LDA(1, et);
    #pragma unroll
    for (int nt = 0; nt < 8; ++nt) w0[nt] = LDW(0, nt);

#define K2_MFMA(AF, WB)                                                                    \
    _Pragma("unroll")                                                                      \
    for (int nt = 0; nt < 8; ++nt)                                                         \
        _Pragma("unroll")                                                                  \
        for (int et = 0; et < 4; ++et)                                                     \
            acc[et][nt] = __builtin_amdgcn_mfma_f32_16x16x32_bf16(AF[et], WB[nt],          \
                                                                  acc[et][nt], 0, 0, 0);
    // ks = 0: prefetch w(1), compute with afX/w0, then refill afX with ks=2
    #pragma unroll
    for (int nt = 0; nt < 8; ++nt) w1[nt] = LDW(1, nt);
    K2_MFMA(afX, w0)
    #pragma unroll
    for (int et = 0; et < 4; ++et) afX[et] = LDA(2, et);
    // ks = 1: prefetch w(2), compute afY/w1, refill afY with ks=3
    #pragma unroll
    for (int nt = 0; nt < 8; ++nt) w0[nt] = LDW(2, nt);
    K2_MFMA(afY, w1)
    #pragma unroll
    for (int et = 0; et < 4; ++et) afY[et] = LDA(3, et);
    // ks = 2: prefetch w(3), compute afX/w0
    #pragma unroll
    for (int nt = 0; nt < 8; ++nt) w1[nt] = LDW(3, nt);
    K2_MFMA(afX, w0)
    // ks = 3
    K2_MFMA(afY, w1)
#undef K2_MFMA
#undef LDA
#undef LDW

    // stage ctx row into LDS: [c][e] bf16, byte ^= ((c&7)<<4) (2-way banks, free)
    char* srow = sC + wv * 16384;
    #pragma unroll
    for (int et = 0; et < 4; ++et)
        #pragma unroll
        for (int nt = 0; nt < 8; ++nt) {
            const int cloc = nt * 16 + lm;
            const uint32_t u0 = (uint32_t)bfbits(acc[et][nt][0]) | ((uint32_t)bfbits(acc[et][nt][1]) << 16);
            const uint32_t u1 = (uint32_t)bfbits(acc[et][nt][2]) | ((uint32_t)bfbits(acc[et][nt][3]) << 16);
            uint32_t bo = (uint32_t)cloc * 128u + (uint32_t)(et * 16 + lg * 4) * 2u;
            bo ^= (uint32_t)(cloc & 7) << 4;
            *(uint2*)(srow + bo) = make_uint2(u0, u1);
        }
    __syncthreads();

    // coalesced writeout: 64 KB = 4096 x 16B units; un-swizzle per unit
    #pragma unroll
    for (int it = 0; it < 16; ++it) {
        const int unit = t + it * 256;             // global 16B-unit in block tile
        const int row = unit >> 10;                // 1024 units per row
        const int u = unit & 1023;                 // c = u>>3, echunk = u&7
        const uint32_t lb = (uint32_t)row * 16384u +
                            (((uint32_t)u * 16u) ^ ((((uint32_t)u >> 3) & 7u) << 4));
        const uint4 val = *(const uint4*)(sC + lb);
        ((uint4*)cbuf)[((rbase + row) << 10) + u] = val;
    }
}

// ---------- K3: out = P2 . relu(P1 @ ctx + pb1) + pb2, MFMA, LDS-staged (R3-verified) ----------
// block = 64 rows x 8 columns, 8 waves (1 column each). M=r (4 tiles), N=f, K=e.
__global__ __launch_bounds__(512) void k3_out(
        const uint32_t* __restrict__ cbuf, const unsigned short* __restrict__ P1hi,
        const unsigned short* __restrict__ P1lo, const float* __restrict__ pb1,
        const float* __restrict__ P2, const float* __restrict__ pb2,
        float* __restrict__ out, int rowOff) {
    __shared__ char sC[64 * 1024];          // [r][c_local][e] bf16, 64KB, XOR-swizzled
    const int t = threadIdx.x;
    const int cg = blockIdx.x;              // 16 groups of 8 columns
    const int r0 = blockIdx.y * 64;         // chunk-local
    const int lane = t & 63, wv = t >> 6;
    const int lm = lane & 15, lg = lane >> 4;
    const int cl = wv;
    const int c = cg * 8 + cl;

    // stage ctx[r0..r0+63][cg*8..+8][all e] coalesced: 1KB contiguous per row
    {
        const int rr = t >> 6;              // 8 rows per pass
        const int inner = t & 63;           // 16B chunk within the 1KB c-window
        #pragma unroll
        for (int p = 0; p < 8; ++p) {
            const int r = p * 8 + rr;
            const uint4 val = *(const uint4*)((const char*)cbuf +
                (size_t)(r0 + r) * 16384 + (size_t)cg * 1024 + (size_t)inner * 16);
            const uint32_t bo = ((uint32_t)r * 1024u + (uint32_t)inner * 16u) ^ ((uint32_t)(r & 7) << 4);
            *(uint4*)(sC + bo) = val;
        }
    }
    __syncthreads();

    float pb1r[4], p2r[4];
    #pragma unroll
    for (int nt = 0; nt < 4; ++nt) {
        pb1r[nt] = pb1[(size_t)c * 64 + nt * 16 + lm];
        p2r[nt]  = P2[(size_t)c * 64 + nt * 16 + lm];
    }
    const float pb2c = pb2[c];

    f32x4 acc[4][4];                        // [mt][nt]
    #pragma unroll
    for (int mt = 0; mt < 4; ++mt)
        #pragma unroll
        for (int nt = 0; nt < 4; ++nt)
            acc[mt][nt] = (f32x4){0.f, 0.f, 0.f, 0.f};

    #pragma unroll
    for (int ks = 0; ks < 2; ++ks) {
        short8 a[4];
        #pragma unroll
        for (int mt = 0; mt < 4; ++mt) {
            const int rl = mt * 16 + lm;
            const uint32_t bo = ((uint32_t)rl * 1024u + (uint32_t)cl * 128u +
                                 (uint32_t)ks * 64u + (uint32_t)lg * 16u) ^ ((uint32_t)(rl & 7) << 4);
            a[mt] = *(const short8*)(sC + bo);
        }
        #pragma unroll
        for (int nt = 0; nt < 4; ++nt) {
            const size_t wb = ((size_t)c * 64 + nt * 16 + lm) * 64 + ks * 32 + lg * 8;
            const short8 bh = *(const short8*)(P1hi + wb);
            const short8 bl = *(const short8*)(P1lo + wb);
            #pragma unroll
            for (int mt = 0; mt < 4; ++mt) {
                acc[mt][nt] = __builtin_amdgcn_mfma_f32_16x16x32_bf16(a[mt], bh, acc[mt][nt], 0, 0, 0);
                acc[mt][nt] = __builtin_amdgcn_mfma_f32_16x16x32_bf16(a[mt], bl, acc[mt][nt], 0, 0, 0);
            }
        }
    }

    // epilogue: relu, dot with P2 over f (lane-local nt + butterfly over lm), store
    #pragma unroll
    for (int mt = 0; mt < 4; ++mt)
        #pragma unroll
        for (int i = 0; i < 4; ++i) {
            float p = 0.f;
            #pragma unroll
            for (int nt = 0; nt < 4; ++nt)
                p = fmaf(fmaxf(acc[mt][nt][i] + pb1r[nt], 0.f), p2r[nt], p);
            p += __shfl_xor(p, 1); p += __shfl_xor(p, 2);
            p += __shfl_xor(p, 4); p += __shfl_xor(p, 8);
            if (lm == 0)
                out[(size_t)(rowOff + r0 + mt * 16 + lg * 4 + i) * C_DIM + c] = p + pb2c;
        }
}

// ---------- host ----------
extern "C" void kernel_launch(void* const* d_in, const int* in_sizes, int n_in,
                              void* d_out, int out_size, void* d_ws, size_t ws_size,
                              hipStream_t stream) {
    const float* samples = (const float*)d_in[0];
    const float* W1  = (const float*)d_in[1];
    const float* b1  = (const float*)d_in[2];
    const float* W2  = (const float*)d_in[3];
    const float* b2  = (const float*)d_in[4];
    const float* q   = (const float*)d_in[5];
    const float* P1  = (const float*)d_in[6];
    const float* pb1 = (const float*)d_in[7];
    const float* P2  = (const float*)d_in[8];
    const float* pb2 = (const float*)d_in[9];
    float* out = (float*)d_out;

    char* ws = (char*)d_ws;
    unsigned short* whi  = (unsigned short*)ws;                       // 32KB
    unsigned short* wlo  = (unsigned short*)(ws + 32768);             // 32KB (unused downstream)
    unsigned short* W2hi = (unsigned short*)(ws + 65536);             // 1MB
    unsigned short* W2lo = (unsigned short*)(ws + 65536 + 1048576);   // 1MB
    unsigned short* P1hi = (unsigned short*)(ws + 65536 + 2097152);   // 1MB
    unsigned short* P1lo = (unsigned short*)(ws + 65536 + 3145728);   // 1MB
    const size_t head = 65536 + 4194304;

    // two regions: V and ctx, each maxRows*16KB
    size_t avail = (ws_size > head) ? ws_size - head : 0;
    long maxRows = (long)(avail / ((size_t)2 * C_DIM * E_DIM * 2));
    maxRows = (maxRows / 256) * 256;
    if (maxRows > B_DIM) maxRows = B_DIM;
    if (maxRows < 256) maxRows = 256;

    uint32_t* vbuf = (uint32_t*)(ws + head);
    uint32_t* cbuf = (uint32_t*)(ws + head + (size_t)maxRows * 16384);

    k0_softmax<<<dim3(C_DIM), dim3(C_DIM), 0, stream>>>(q, whi, wlo);
    kP_split<<<dim3(512), 256, 0, stream>>>(W2, W2hi, W2lo);   // 524288 floats / 4 / 256
    kP_split<<<dim3(512), 256, 0, stream>>>(P1, P1hi, P1lo);

    for (int off = 0; off < B_DIM; off += (int)maxRows) {
        const int rows = (int)(((long)(B_DIM - off) < maxRows) ? (long)(B_DIM - off) : maxRows);
        k1_value<<<dim3(rows / 64, 16), 512, 0, stream>>>(samples, W1, b1, W2hi, W2lo, b2, vbuf, off);
        k2_ctx<<<dim3(rows / 4), 256, 0, stream>>>(whi, vbuf, cbuf);
        k3_out<<<dim3(16, rows / 64), 512, 0, stream>>>(cbuf, P1hi, P1lo, pb1, P2, pb2, out, off);
    }
}